// Round 4
// baseline (1029.215 us; speedup 1.0000x reference)
//
#include <hip/hip_runtime.h>
#include <hip/hip_cooperative_groups.h>
#include <math.h>

namespace cg = cooperative_groups;

typedef __attribute__((ext_vector_type(8))) short short8;
typedef __attribute__((ext_vector_type(4))) float float4v;

#define QS 0.2550354f   // (1/sqrt(32)) * log2(e), folded into wq/bq; exp via raw v_exp
#define NB 512          // cooperative grid: 512 blocks x 256 threads, co-resident (2/CU)

#if __has_builtin(__builtin_amdgcn_exp2f)
#define EXP2(x) __builtin_amdgcn_exp2f(x)
#else
#define EXP2(x) __expf((x)*0.6931471805599453f)
#endif

__device__ __forceinline__ float waveReduceSum(float v){
  #pragma unroll
  for(int o=32;o>0;o>>=1) v += __shfl_down(v,o,64);
  return v;
}
__device__ __forceinline__ unsigned short f2bf(float f){
  unsigned int u = __float_as_uint(f);
  return (unsigned short)((u + 0x7FFFu + ((u>>16)&1u)) >> 16);
}
__device__ __forceinline__ float bf2f(unsigned short u){
  return __uint_as_float(((unsigned int)u)<<16);
}

struct MP {
  const float* x; const int* ei;
  const float *W0,*as0,*ad0,*b0;
  const float *W1,*as1,*ad1,*b1;
  const float *W2,*as2,*ad2,*b2;
  const float *g0,*be0,*g1,*be1,*g2,*be2;
  const float *wq,*bq,*wk,*bk,*wv,*bv,*wo,*bo;
  float* out;
  float *h0,*als,*ald,*bqkv;
  unsigned short *xb,*xlb,*h0b,*h1b,*h2b,*QKVb,*Vt,*aob;
  unsigned short *W0t,*W1t,*W2t,*wqkvt,*wot,*Wsd0,*Wsd1,*Wsd2;
  int *hist,*wcnt,*rp,*col;
  int E, Etot;
};

// ---------------- phase helpers (all operate on the shared smem pool) ----------------

// weight transpose via LDS tile (unit tb in [0,176))
__device__ void transpose_unit(int tb, const MP& P, char* smem){
  int t = threadIdx.x;
  unsigned short (*tile)[65] = (unsigned short(*)[65])smem;
  const float* src; unsigned short* dst; int K,N,roff,local; float sc = 1.f;
  if(tb<16){src=P.W0;dst=P.W0t;K=128;N=512;local=tb;roff=0;}
  else if(tb<80){src=P.W1;dst=P.W1t;K=512;N=512;local=tb-16;roff=0;}
  else if(tb<112){src=P.W2;dst=P.W2t;K=512;N=256;local=tb-80;roff=0;}
  else if(tb<128){src=P.wq;dst=P.wqkvt;K=256;N=256;local=tb-112;roff=0;sc=QS;}
  else if(tb<144){src=P.wk;dst=P.wqkvt;K=256;N=256;local=tb-128;roff=256;}
  else if(tb<160){src=P.wv;dst=P.wqkvt;K=256;N=256;local=tb-144;roff=512;}
  else {src=P.wo;dst=P.wot;K=256;N=256;local=tb-160;roff=0;}
  int ntiles = N>>6;
  int k0 = (local/ntiles)*64, n0 = (local%ntiles)*64;
  int r4 = t>>4, c4 = (t&15)*4;
  #pragma unroll
  for(int it=0;it<4;it++){
    int row = r4 + it*16;
    float4 v = *(const float4*)(src + (size_t)(k0+row)*N + n0 + c4);
    tile[row][c4+0]=f2bf(v.x*sc);
    tile[row][c4+1]=f2bf(v.y*sc);
    tile[row][c4+2]=f2bf(v.z*sc);
    tile[row][c4+3]=f2bf(v.w*sc);
  }
  __syncthreads();
  int r8 = t>>3, c8 = (t&7)*8;
  #pragma unroll
  for(int it=0;it<2;it++){
    int n = r8 + it*32;
    short8 o;
    #pragma unroll
    for(int j=0;j<8;j++) o[j] = (short)tile[c8+j][n];
    *(short8*)(dst + (size_t)(n0+n+roff)*K + k0 + c8) = o;
  }
}

// Wsd build (unit bb in [0,1152))
__device__ void wsd_unit(int bb, const MP& P, char* smem){
  int t = threadIdx.x;
  float* s1 = (float*)smem; float* s2 = s1+4;
  const float *W,*as,*ad; unsigned short* S; int K,C,H,k;
  if(bb<128){W=P.W0;as=P.as0;ad=P.ad0;S=P.Wsd0;K=128;C=128;H=4;k=bb;}
  else if(bb<640){W=P.W1;as=P.as1;ad=P.ad1;S=P.Wsd1;K=512;C=128;H=4;k=bb-128;}
  else {W=P.W2;as=P.as2;ad=P.ad2;S=P.Wsd2;K=512;C=256;H=1;k=bb-640;}
  int D = H*C;
  int lane=t&63, wid=t>>6;
  for(int h=0;h<H;h++){
    float ps=0.f, pd=0.f;
    for(int c=t;c<C;c+=256){
      float wv2 = W[k*D + h*C + c];
      ps += wv2*as[h*C+c];
      pd += wv2*ad[h*C+c];
    }
    ps = waveReduceSum(ps); pd = waveReduceSum(pd);
    if(lane==0){ s1[wid]=ps; s2[wid]=pd; }
    __syncthreads();
    if(t==0){
      float u=s1[0]+s1[1]+s1[2]+s1[3], v=s2[0]+s2[1]+s2[2]+s2[3];
      S[h*K+k]=f2bf(u); S[(4+h)*K+k]=f2bf(v);
    }
    __syncthreads();
  }
  if(t==0){
    for(int h=H;h<4;h++){ S[h*K+k]=0; S[(4+h)*K+k]=0; }
    for(int r=8;r<16;r++) S[r*K+k]=0;
  }
}

// single-block exclusive scan of hist[4096] -> rp/wcnt (256 threads, 16/thread)
__device__ void scan_block(const int* __restrict__ hist, int* __restrict__ rp,
                           int* __restrict__ wcnt, char* smem){
  int t = threadIdx.x;
  int* sh = (int*)smem;
  int loc[16]; int s=0;
  #pragma unroll
  for(int i=0;i<16;i++){ loc[i]=s; s += hist[t*16+i]; }
  sh[t] = s;
  __syncthreads();
  for(int off=1; off<256; off<<=1){
    int x = (t>=off) ? sh[t-off] : 0;
    __syncthreads();
    sh[t] += x;
    __syncthreads();
  }
  int excl = (t==0) ? 0 : sh[t-1];
  #pragma unroll
  for(int i=0;i<16;i++){
    int v = excl + loc[i];
    rp[t*16+i] = v; wcnt[t*16+i] = v;
  }
  if(t==255) rp[4096] = excl + s;
}

// MFMA bf16 GEMM tile (double-buffered LDS), unit u -> (bx,by)
__device__ void gemm_unit(int u, int nbx,
                          const unsigned short* __restrict__ A, const unsigned short* __restrict__ Bt,
                          const float* __restrict__ bias, float* __restrict__ C,
                          unsigned short* __restrict__ Cb, unsigned short* __restrict__ VtT,
                          const unsigned short* __restrict__ Wsd, float* __restrict__ als,
                          float* __restrict__ ald, int M, int K, int N, char* smem){
  int t = threadIdx.x, lane = t & 63, w = t >> 6;
  int m = lane & 15, g = lane >> 4;
  int bx = u % nbx, by = u / nbx;
  int bm = by * 64, bn = bx * 64;
  unsigned short* As = (unsigned short*)smem;           // [2][64*72]
  unsigned short* Bs = (unsigned short*)(smem + 18432); // [2][64*72]

  int sr = t >> 3;
  int sc = (t & 7) * 8;
  const unsigned short* Ap = A  + (size_t)(bm + sr)*K + sc;
  const unsigned short* Bp = Bt + (size_t)(bn + sr)*K + sc;
  bool doC = (Wsd != nullptr) && (bx == 0);

  float4v acc[4];
  #pragma unroll
  for(int nt=0;nt<4;nt++) acc[nt] = (float4v){0.f,0.f,0.f,0.f};
  float4v acc2 = (float4v){0.f,0.f,0.f,0.f};

  short8 a0 = *(const short8*)(Ap);
  short8 a1 = *(const short8*)(Ap + 32*K);
  short8 b0 = *(const short8*)(Bp);
  short8 b1 = *(const short8*)(Bp + 32*K);

  int buf = 0;
  for(int k0=0;k0<K;k0+=64){
    *(short8*)&As[buf*4608 + sr*72 + sc]      = a0;
    *(short8*)&As[buf*4608 + (sr+32)*72 + sc] = a1;
    *(short8*)&Bs[buf*4608 + sr*72 + sc]      = b0;
    *(short8*)&Bs[buf*4608 + (sr+32)*72 + sc] = b1;
    if(k0+64 < K){
      a0 = *(const short8*)(Ap + k0+64);
      a1 = *(const short8*)(Ap + 32*K + k0+64);
      b0 = *(const short8*)(Bp + k0+64);
      b1 = *(const short8*)(Bp + 32*K + k0+64);
    }
    __syncthreads();

    #pragma unroll
    for(int ks=0;ks<2;ks++){
      short8 aA = *(const short8*)&As[buf*4608 + (w*16 + m)*72 + ks*32 + g*8];
      #pragma unroll
      for(int nt=0;nt<4;nt++){
        short8 bB = *(const short8*)&Bs[buf*4608 + (nt*16 + m)*72 + ks*32 + g*8];
        acc[nt] = __builtin_amdgcn_mfma_f32_16x16x32_bf16(aA, bB, acc[nt], 0,0,0);
      }
      if(doC){
        short8 bW = *(const short8*)(Wsd + m*K + k0 + ks*32 + g*8);
        acc2 = __builtin_amdgcn_mfma_f32_16x16x32_bf16(aA, bW, acc2, 0,0,0);
      }
    }
    buf ^= 1;
  }

  if(VtT != nullptr && bn >= 512){
    __syncthreads();
    unsigned short* T = As;
    #pragma unroll
    for(int nt=0;nt<4;nt++){
      int col = bn + nt*16 + m;
      float bv = bias ? bias[col] : 0.f;
      unsigned int r0 = __float_as_uint(acc[nt][0]+bv) + 0x8000u;
      unsigned int r1 = __float_as_uint(acc[nt][1]+bv) + 0x8000u;
      unsigned int r2 = __float_as_uint(acc[nt][2]+bv) + 0x8000u;
      unsigned int r3 = __float_as_uint(acc[nt][3]+bv) + 0x8000u;
      uint2 pk;
      pk.x = __builtin_amdgcn_perm(r1, r0, 0x07060302u);
      pk.y = __builtin_amdgcn_perm(r3, r2, 0x07060302u);
      *(uint2*)&T[(nt*16 + m)*72 + w*16 + g*4] = pk;
    }
    __syncthreads();
    int d  = t >> 2;
    int qc = (t & 3) * 16;
    short8 v0 = *(const short8*)&T[d*72 + qc];
    short8 v1 = *(const short8*)&T[d*72 + qc + 8];
    unsigned short* dst = VtT + (size_t)(bn - 512 + d)*M + bm + qc;
    *(short8*)(dst)     = v0;
    *(short8*)(dst + 8) = v1;
  } else {
    #pragma unroll
    for(int nt=0;nt<4;nt++){
      int col = bn + nt*16 + m;
      float bv = bias ? bias[col] : 0.f;
      #pragma unroll
      for(int r=0;r<4;r++){
        int row = bm + w*16 + g*4 + r;
        float v = acc[nt][r] + bv;
        if(C)  C[(size_t)row*N + col]  = v;
        if(Cb) Cb[(size_t)row*N + col] = f2bf(v);
      }
    }
    if(doC){
      #pragma unroll
      for(int r=0;r<4;r++){
        int row = bm + w*16 + g*4 + r;
        if(m<4)      als[row*4 + m]     = acc2[r];
        else if(m<8) ald[row*4 + (m-4)] = acc2[r];
      }
    }
  }
  __syncthreads();  // LDS reuse guard for back-to-back units in one block
}

// fused GAT gather + softmax + bias + ELU + LayerNorm (+residual), one node
#define CE 128
__device__ void gat_node(int n, const int* __restrict__ rp, const int* __restrict__ col,
                         const unsigned short* __restrict__ xlb,
                         const float* __restrict__ als, const float* __restrict__ ald,
                         const float* __restrict__ bias, const float* __restrict__ gw,
                         const float* __restrict__ be, const float* __restrict__ res,
                         float* __restrict__ out, unsigned short* __restrict__ outb,
                         int D, int logC, int do_elu, int nw, char* smem){
  int t = threadIdx.x;
  float* pw  = (float*)smem;                 // [2][CE*4]
  int*  offs = (int*)(smem + 4096);          // [2][CE]
  float* shv = (float*)(smem + 4096 + 1024); // [4]
  int halfD = D >> 1;
  bool act = t < halfD;
  int c0 = t*2;
  int h = c0 >> logC;                        // wave-uniform; <=1 even for idle lanes (layer2)
  float4 advv = *(const float4*)(ald + n*4);
  int start = rp[n], end = rp[n+1];
  const unsigned int* xw = (const unsigned int*)xlb;

  float acc0=0.f, acc1=0.f, den=0.f;
  int nch = (end - start + CE - 1) / CE;

  {
    int cnt = min(CE, end-start);
    if(t < cnt){
      int s = col[start+t];
      offs[t] = s*halfD;
      float4 av = *(const float4*)(als + s*4);
      #pragma unroll
      for(int hh=0;hh<4;hh++){
        float a = ((const float*)&av)[hh] + ((const float*)&advv)[hh];
        a = a>0.f ? a : 0.2f*a;
        pw[t*4+hh] = __expf(a);
      }
    }
  }

  for(int c=0;c<nch;c++){
    __syncthreads();
    if(c+1 < nch){
      int base2 = start + (c+1)*CE;
      int cnt = min(CE, end-base2);
      int b2 = (c+1)&1;
      if(t < cnt){
        int s = col[base2+t];
        offs[b2*CE+t] = s*halfD;
        float4 av = *(const float4*)(als + s*4);
        #pragma unroll
        for(int hh=0;hh<4;hh++){
          float a = ((const float*)&av)[hh] + ((const float*)&advv)[hh];
          a = a>0.f ? a : 0.2f*a;
          pw[b2*CE*4 + t*4+hh] = __expf(a);
        }
      }
    }
    int base = start + c*CE;
    int cnt = min(CE, end-base);
    int b = c&1;
    #pragma unroll 8
    for(int j=0;j<cnt;j++){
      float p = pw[b*CE*4 + j*4+h];
      unsigned int u = xw[offs[b*CE+j] + t];   // idle lanes read in-bounds garbage
      acc0 += p * bf2f((unsigned short)(u & 0xffffu));
      acc1 += p * bf2f((unsigned short)(u >> 16));
      den += p;
    }
  }

  float v0=0.f, v1=0.f;
  if(act){
    float inv_d = 1.f/(den + 1e-16f);
    v0 = acc0*inv_d + bias[c0];
    v1 = acc1*inv_d + bias[c0+1];
    if(do_elu){
      v0 = v0>0.f ? v0 : expm1f(v0);
      v1 = v1>0.f ? v1 : expm1f(v1);
    }
  }
  int lane=t&63, wid=t>>6;
  float sum = waveReduceSum(v0+v1);
  if(lane==0) shv[wid]=sum;
  __syncthreads();
  float mean = 0.f;
  for(int i=0;i<nw;i++) mean += shv[i];
  mean /= (float)D;
  __syncthreads();
  float d0 = act ? v0-mean : 0.f;
  float d1 = act ? v1-mean : 0.f;
  float vs = waveReduceSum(d0*d0 + d1*d1);
  if(lane==0) shv[wid]=vs;
  __syncthreads();
  float var = 0.f;
  for(int i=0;i<nw;i++) var += shv[i];
  var /= (float)D;
  float inv = rsqrtf(var + 1e-5f);
  if(act){
    float y0 = d0*inv*gw[c0]   + be[c0];
    float y1 = d1*inv*gw[c0+1] + be[c0+1];
    if(res){ float2 rv = *(const float2*)(res + (size_t)n*D + c0); y0 += rv.x; y1 += rv.y; }
    if(out) *(float2*)(out + (size_t)n*D + c0) = make_float2(y0, y1);
    if(outb) ((unsigned int*)outb)[(size_t)n*halfD + t] =
        (unsigned int)f2bf(y0) | ((unsigned int)f2bf(y1) << 16);
  }
}

// MFMA bf16 MHA, full K-range per unit (u = qb_idx*8 + h), writes aob directly
__device__ void attn_unit(int u, const unsigned short* __restrict__ QKV,
                          const unsigned short* __restrict__ Vt,
                          unsigned short* __restrict__ aob, int S, char* smem){
  const int RS = 768;
  int qb = (u >> 3) * 64;
  int h  = u & 7;
  int t  = threadIdx.x;
  int lane = t & 63, w = t >> 6;
  int m = lane & 15, g = lane >> 4;
  int m7 = m & 7;

  unsigned short* Ps = (unsigned short*)smem;          // 64*64
  unsigned short* Vs = (unsigned short*)(smem + 8192); // 32*64
  unsigned short* Ks = (unsigned short*)(smem + 12288);// 64*36

  short8 aQ = *(const short8*)(QKV + (size_t)(qb + w*16 + m)*RS + h*32 + g*8);

  float4v o0 = {0.f,0.f,0.f,0.f}, o1 = {0.f,0.f,0.f,0.f};
  float den = 0.f;

  int r8 = t>>3, c8 = t&7;
  int kr = t>>2, kc = (t&3)*8;

  // prologue prefetch
  short8 v  = *(const short8*)(Vt + (size_t)(h*32 + r8)*S + c8*8);
  short8 kv = *(const short8*)(QKV + (size_t)kr*RS + 256 + h*32 + kc);

  for(int kt=0; kt<S; kt+=64){
    __syncthreads();
    *(short8*)&Vs[r8*64 + ((c8 ^ (r8&7))<<3)] = v;
    *(short8*)&Ks[kr*36 + kc] = kv;
    if(kt+64 < S){
      v  = *(const short8*)(Vt + (size_t)(h*32 + r8)*S + kt+64 + c8*8);
      kv = *(const short8*)(QKV + (size_t)(kt+64 + kr)*RS + 256 + h*32 + kc);
    }
    __syncthreads();

    #pragma unroll
    for(int nt=0;nt<4;nt++){
      short8 aK = *(const short8*)&Ks[(nt*16 + m)*36 + g*8];
      float4v acc = {0.f,0.f,0.f,0.f};
      acc = __builtin_amdgcn_mfma_f32_16x16x32_bf16(aK, aQ, acc, 0,0,0);
      float p0 = EXP2(acc[0]);
      float p1 = EXP2(acc[1]);
      float p2 = EXP2(acc[2]);
      float p3 = EXP2(acc[3]);
      den += (p0+p1)+(p2+p3);
      unsigned int r0 = __float_as_uint(p0) + 0x8000u;
      unsigned int r1 = __float_as_uint(p1) + 0x8000u;
      unsigned int r2 = __float_as_uint(p2) + 0x8000u;
      unsigned int r3 = __float_as_uint(p3) + 0x8000u;
      uint2 pk;
      pk.x = __builtin_amdgcn_perm(r1, r0, 0x07060302u);
      pk.y = __builtin_amdgcn_perm(r3, r2, 0x07060302u);
      *(uint2*)&Ps[(w*16 + m)*64 + (((2*nt + (g>>1)) ^ m7)<<3) + ((g&1)<<2)] = pk;
    }

    #pragma unroll
    for(int kh=0;kh<2;kh++){
      int swz = ((kh*4 + g) ^ m7) << 3;
      short8 aP  = *(const short8*)&Ps[(w*16 + m)*64 + swz];
      short8 bV0 = *(const short8*)&Vs[m*64       + swz];
      short8 bV1 = *(const short8*)&Vs[(16+m)*64  + swz];
      o0 = __builtin_amdgcn_mfma_f32_16x16x32_bf16(aP, bV0, o0, 0,0,0);
      o1 = __builtin_amdgcn_mfma_f32_16x16x32_bf16(aP, bV1, o1, 0,0,0);
    }
  }

  // full softmax denominator for q = w*16+m (replicated across g)
  den += __shfl_xor(den, 16, 64);
  den += __shfl_xor(den, 32, 64);

  #pragma unroll
  for(int r=0;r<4;r++){
    float dd = __shfl(den, g*4 + r, 64);   // lane g*4+r holds den for row g*4+r
    int q = qb + w*16 + g*4 + r;
    aob[(size_t)q*256 + h*32 + m]      = f2bf(o0[r]/dd);
    aob[(size_t)q*256 + h*32 + 16 + m] = f2bf(o1[r]/dd);
  }
}

// ---------------- the single cooperative kernel ----------------
__global__ __launch_bounds__(256, 2) void mega(MP P){
  __shared__ __attribute__((aligned(16))) char smem[36880];
  cg::grid_group grid = cg::this_grid();
  int blk = blockIdx.x, t = threadIdx.x;

  // ---- phase 0: zero hist + x->bf16 + bqkv + weight transposes + Wsd ----
  { int gid = blk*256 + t; if(gid < 4096) P.hist[gid] = 0; }
  for(int u=blk; u<1585; u+=NB){
    if(u < 256){
      int i = (u*256 + t)*8;
      float4 u0 = *(const float4*)(P.x + i);
      float4 u1 = *(const float4*)(P.x + i + 4);
      short8 o;
      o[0]=(short)f2bf(u0.x); o[1]=(short)f2bf(u0.y); o[2]=(short)f2bf(u0.z); o[3]=(short)f2bf(u0.w);
      o[4]=(short)f2bf(u1.x); o[5]=(short)f2bf(u1.y); o[6]=(short)f2bf(u1.z); o[7]=(short)f2bf(u1.w);
      *(short8*)(P.xb + i) = o;
    } else if(u == 256){
      P.bqkv[t] = P.bq[t]*QS; P.bqkv[256+t] = P.bk[t]; P.bqkv[512+t] = P.bv[t];
    } else if(u < 433){
      transpose_unit(u-257, P, smem);   // 176 units exactly
    } else {
      wsd_unit(u-433, P, smem);         // 1152 units: [433, 1585)
    }
    __syncthreads();
  }
  grid.sync();

  // ---- phase 1: hist count ----
  for(int u=blk; u<528; u+=NB){
    int e = u*256 + t;
    if(e < P.Etot){
      int d = (e < P.E) ? (P.ei[P.E+e] & 4095) : (e - P.E);
      atomicAdd(&P.hist[d], 1);
    }
  }
  grid.sync();

  // ---- phase 2: CSR scan (block 0 only) ----
  if(blk == 0) scan_block(P.hist, P.rp, P.wcnt, smem);
  grid.sync();

  // ---- phase 3: CSR scatter || GEMM layer0 (independent) ----
  for(int u=blk; u<1040; u+=NB){
    if(u < 512){
      gemm_unit(u, 8, P.xb, P.W0t, nullptr, nullptr, P.xlb, nullptr,
                P.Wsd0, P.als, P.ald, 4096, 128, 512, smem);
    } else {
      int e = (u-512)*256 + t;
      if(e < P.Etot){
        int s,d;
        if(e < P.E){ s = P.ei[e]&4095; d = P.ei[P.E+e]&4095; } else { s = d = e - P.E; }
        int pos = atomicAdd(&P.wcnt[d], 1);
        P.col[pos] = s;
      }
      __syncthreads();
    }
  }
  grid.sync();

  // ---- phase 4: gather layer0 ----
  for(int n=blk; n<4096; n+=NB)
    gat_node(n, P.rp, P.col, P.xlb, P.als, P.ald, P.b0, P.g0, P.be0,
             nullptr, P.h0, P.h0b, 512, 7, 1, 4, smem);
  grid.sync();

  // ---- phase 5: GEMM layer1 ----
  for(int u=blk; u<512; u+=NB)
    gemm_unit(u, 8, P.h0b, P.W1t, nullptr, nullptr, P.xlb, nullptr,
              P.Wsd1, P.als, P.ald, 4096, 512, 512, smem);
  grid.sync();

  // ---- phase 6: gather layer1 (+residual h0) ----
  for(int n=blk; n<4096; n+=NB)
    gat_node(n, P.rp, P.col, P.xlb, P.als, P.ald, P.b1, P.g1, P.be1,
             P.h0, nullptr, P.h1b, 512, 7, 1, 4, smem);
  grid.sync();

  // ---- phase 7: GEMM layer2 ----
  for(int u=blk; u<256; u+=NB)
    gemm_unit(u, 4, P.h1b, P.W2t, nullptr, nullptr, P.xlb, nullptr,
              P.Wsd2, P.als, P.ald, 4096, 512, 256, smem);
  grid.sync();

  // ---- phase 8: gather layer2 (1 head, no ELU) ----
  for(int n=blk; n<4096; n+=NB)
    gat_node(n, P.rp, P.col, P.xlb, P.als, P.ald, P.b2, P.g2, P.be2,
             nullptr, nullptr, P.h2b, 256, 8, 0, 2, smem);
  grid.sync();

  // ---- phase 9: QKV GEMM (w/ tiled V-transpose epilogue) ----
  for(int u=blk; u<768; u+=NB)
    gemm_unit(u, 12, P.h2b, P.wqkvt, P.bqkv, nullptr, P.QKVb, P.Vt,
              nullptr, nullptr, nullptr, 4096, 256, 768, smem);
  grid.sync();

  // ---- phase 10: attention (full K per unit; writes aob incl. softmax div) ----
  attn_unit(blk, P.QKVb, P.Vt, P.aob, 4096, smem);
  grid.sync();

  // ---- phase 11: output projection ----
  for(int u=blk; u<256; u+=NB)
    gemm_unit(u, 4, P.aob, P.wot, P.bo, P.out, nullptr, nullptr,
              nullptr, nullptr, nullptr, 4096, 256, 256, smem);
}

extern "C" void kernel_launch(void* const* d_in, const int* in_sizes, int n_in,
                              void* d_out, int out_size, void* d_ws, size_t ws_size,
                              hipStream_t stream) {
  const int N = 4096;
  const int E = in_sizes[1] / 2;
  const int Etot = E + N;

  char* p = (char*)d_ws;
  auto alloc = [&](size_t bytes){ char* r = p; p += (bytes + 255) & ~(size_t)255; return r; };

  MP P;
  P.x   = (const float*)d_in[0];
  P.ei  = (const int*)d_in[1];
  P.W0  = (const float*)d_in[2];
  P.as0 = (const float*)d_in[3];
  P.ad0 = (const float*)d_in[4];
  P.b0  = (const float*)d_in[5];
  P.W1  = (const float*)d_in[6];
  P.as1 = (const float*)d_in[7];
  P.ad1 = (const float*)d_in[8];
  P.b1  = (const float*)d_in[9];
  P.W2  = (const float*)d_in[10];
  P.as2 = (const float*)d_in[11];
  P.ad2 = (const float*)d_in[12];
  P.b2  = (const float*)d_in[13];
  P.g0  = (const float*)d_in[14];
  P.be0 = (const float*)d_in[15];
  P.g1  = (const float*)d_in[16];
  P.be1 = (const float*)d_in[17];
  P.g2  = (const float*)d_in[18];
  P.be2 = (const float*)d_in[19];
  P.wq  = (const float*)d_in[20];
  P.bq  = (const float*)d_in[21];
  P.wk  = (const float*)d_in[22];
  P.bk  = (const float*)d_in[23];
  P.wv  = (const float*)d_in[24];
  P.bv  = (const float*)d_in[25];
  P.wo  = (const float*)d_in[26];
  P.bo  = (const float*)d_in[27];
  P.out = (float*)d_out;

  P.h0   = (float*)alloc((size_t)N*512*4);
  P.als  = (float*)alloc(N*4*4);
  P.ald  = (float*)alloc(N*4*4);
  P.xb   = (unsigned short*)alloc((size_t)N*128*2);
  P.xlb  = (unsigned short*)alloc((size_t)N*512*2);
  P.h0b  = (unsigned short*)alloc((size_t)N*512*2);
  P.h1b  = (unsigned short*)alloc((size_t)N*512*2);
  P.h2b  = (unsigned short*)alloc((size_t)N*256*2);
  P.QKVb = (unsigned short*)alloc((size_t)N*768*2);
  P.Vt   = (unsigned short*)alloc((size_t)256*N*2);
  P.aob  = (unsigned short*)alloc((size_t)N*256*2);
  P.W0t  = (unsigned short*)alloc(512*128*2);
  P.W1t  = (unsigned short*)alloc(512*512*2);
  P.W2t  = (unsigned short*)alloc(256*512*2);
  P.wqkvt= (unsigned short*)alloc(768*256*2);
  P.bqkv = (float*)alloc(768*4);
  P.wot  = (unsigned short*)alloc(256*256*2);
  P.Wsd0 = (unsigned short*)alloc(16*128*2);
  P.Wsd1 = (unsigned short*)alloc(16*512*2);
  P.Wsd2 = (unsigned short*)alloc(16*512*2);
  P.hist = (int*)alloc(N*4);
  P.wcnt = (int*)alloc(N*4);
  P.rp   = (int*)alloc((N+2)*4);
  P.col  = (int*)alloc((size_t)Etot*4);
  P.E = E; P.Etot = Etot;

  void* kargs[] = { (void*)&P };
  hipLaunchCooperativeKernel((const void*)mega, dim3(NB), dim3(256), kargs, 0, stream);
}

// Round 5
// 301.557 us; speedup vs baseline: 3.4130x; 3.4130x over previous
//
#include <hip/hip_runtime.h>
#include <math.h>

typedef __attribute__((ext_vector_type(8))) short short8;
typedef __attribute__((ext_vector_type(4))) float float4v;

#define QS 0.2550354f   // (1/sqrt(32)) * log2(e), folded into wq/bq; exp via raw v_exp

#if __has_builtin(__builtin_amdgcn_exp2f)
#define EXP2(x) __builtin_amdgcn_exp2f(x)
#else
#define EXP2(x) __expf((x)*0.6931471805599453f)
#endif

__device__ __forceinline__ float waveReduceSum(float v){
  #pragma unroll
  for(int o=32;o>0;o>>=1) v += __shfl_down(v,o,64);
  return v;
}
__device__ __forceinline__ unsigned short f2bf(float f){
  unsigned int u = __float_as_uint(f);
  return (unsigned short)((u + 0x7FFFu + ((u>>16)&1u)) >> 16);
}
__device__ __forceinline__ float bf2f(unsigned short u){
  return __uint_as_float(((unsigned int)u)<<16);
}

// ------- fused prep: x->bf16 (vectorized) + LDS-tiled transposes + qkv concat + Wsd -------
__global__ __launch_bounds__(256) void prep(const float* __restrict__ x, unsigned short* __restrict__ xb,
                     const float* __restrict__ W0, unsigned short* __restrict__ W0t,
                     const float* __restrict__ W1, unsigned short* __restrict__ W1t,
                     const float* __restrict__ W2, unsigned short* __restrict__ W2t,
                     const float* __restrict__ wq, const float* __restrict__ wk,
                     const float* __restrict__ wv, unsigned short* __restrict__ wqkvt,
                     const float* __restrict__ bq, const float* __restrict__ bk,
                     const float* __restrict__ bv, float* __restrict__ bqkv,
                     const float* __restrict__ wo, unsigned short* __restrict__ wot,
                     const float* __restrict__ as0, const float* __restrict__ ad0, unsigned short* __restrict__ S0,
                     const float* __restrict__ as1, const float* __restrict__ ad1, unsigned short* __restrict__ S1,
                     const float* __restrict__ as2, const float* __restrict__ ad2, unsigned short* __restrict__ S2){
  int b = blockIdx.x, t = threadIdx.x;
  if(b < 256){
    // x -> bf16, 8 elems/thread (4096*128 = 524288 = 256*256*8)
    int i = (b*256 + t)*8;
    float4 u0 = *(const float4*)(x + i);
    float4 u1 = *(const float4*)(x + i + 4);
    short8 o;
    o[0]=(short)f2bf(u0.x); o[1]=(short)f2bf(u0.y); o[2]=(short)f2bf(u0.z); o[3]=(short)f2bf(u0.w);
    o[4]=(short)f2bf(u1.x); o[5]=(short)f2bf(u1.y); o[6]=(short)f2bf(u1.z); o[7]=(short)f2bf(u1.w);
    *(short8*)(xb + i) = o;
    return;
  }
  if(b == 256){ bqkv[t] = bq[t]*QS; bqkv[256+t] = bk[t]; bqkv[512+t] = bv[t]; return; }
  if(b < 433){
    __shared__ unsigned short tile[64][65];
    int tb = b - 257;   // 176 transpose units
    const float* src; unsigned short* dst; int K,N,roff,local; float sc = 1.f;
    if(tb<16){src=W0;dst=W0t;K=128;N=512;local=tb;roff=0;}
    else if(tb<80){src=W1;dst=W1t;K=512;N=512;local=tb-16;roff=0;}
    else if(tb<112){src=W2;dst=W2t;K=512;N=256;local=tb-80;roff=0;}
    else if(tb<128){src=wq;dst=wqkvt;K=256;N=256;local=tb-112;roff=0;sc=QS;}
    else if(tb<144){src=wk;dst=wqkvt;K=256;N=256;local=tb-128;roff=256;}
    else if(tb<160){src=wv;dst=wqkvt;K=256;N=256;local=tb-144;roff=512;}
    else {src=wo;dst=wot;K=256;N=256;local=tb-160;roff=0;}
    int ntiles = N>>6;
    int k0 = (local/ntiles)*64, n0 = (local%ntiles)*64;
    int r4 = t>>4, c4 = (t&15)*4;
    #pragma unroll
    for(int it=0;it<4;it++){
      int row = r4 + it*16;
      float4 v = *(const float4*)(src + (size_t)(k0+row)*N + n0 + c4);
      tile[row][c4+0]=f2bf(v.x*sc);
      tile[row][c4+1]=f2bf(v.y*sc);
      tile[row][c4+2]=f2bf(v.z*sc);
      tile[row][c4+3]=f2bf(v.w*sc);
    }
    __syncthreads();
    int r8 = t>>3, c8 = (t&7)*8;
    #pragma unroll
    for(int it=0;it<2;it++){
      int n = r8 + it*32;
      short8 o;
      #pragma unroll
      for(int j=0;j<8;j++) o[j] = (short)tile[c8+j][n];
      *(short8*)(dst + (size_t)(n0+n+roff)*K + k0 + c8) = o;
    }
    return;
  }
  // ---- Wsd build: bb in [0,1152) ----
  int bb = b - 433;
  const float *W,*as,*ad; unsigned short* S; int K,C,H,k;
  if(bb<128){W=W0;as=as0;ad=ad0;S=S0;K=128;C=128;H=4;k=bb;}
  else if(bb<640){W=W1;as=as1;ad=ad1;S=S1;K=512;C=128;H=4;k=bb-128;}
  else {W=W2;as=as2;ad=ad2;S=S2;K=512;C=256;H=1;k=bb-640;}
  int D = H*C;
  __shared__ float s1[4], s2[4];
  int lane=t&63, wid=t>>6;
  for(int h=0;h<H;h++){
    float ps=0.f, pd=0.f;
    for(int c=t;c<C;c+=256){
      float wv2 = W[k*D + h*C + c];
      ps += wv2*as[h*C+c];
      pd += wv2*ad[h*C+c];
    }
    ps = waveReduceSum(ps); pd = waveReduceSum(pd);
    if(lane==0){ s1[wid]=ps; s2[wid]=pd; }
    __syncthreads();
    if(t==0){
      float u=s1[0]+s1[1]+s1[2]+s1[3], v=s2[0]+s2[1]+s2[2]+s2[3];
      S[h*K+k]=f2bf(u); S[(4+h)*K+k]=f2bf(v);
    }
    __syncthreads();
  }
  if(t==0){
    for(int h=H;h<4;h++){ S[h*K+k]=0; S[(4+h)*K+k]=0; }
    for(int r=8;r<16;r++) S[r*K+k]=0;
  }
}

// ---------------- CSR: hist (LDS atomics) + scan in one single-block kernel ----------------
__global__ __launch_bounds__(1024) void csr_scan(const int* __restrict__ ei, int E, int Etot,
                                                 int* __restrict__ rp, int* __restrict__ wcnt){
  __shared__ int sh[1024];
  __shared__ int lhist[4096];
  int t = threadIdx.x;
  #pragma unroll
  for(int i=0;i<4;i++) lhist[t*4+i] = 0;
  __syncthreads();
  for(int e=t; e<Etot; e+=1024){
    int d = (e<E) ? (ei[E+e]&4095) : (e-E);
    atomicAdd(&lhist[d], 1);
  }
  __syncthreads();
  int base[4]; int s=0;
  #pragma unroll
  for(int i=0;i<4;i++){ base[i]=s; s += lhist[t*4+i]; }
  sh[t] = s;
  __syncthreads();
  for(int off=1; off<1024; off<<=1){
    int x = (t>=off) ? sh[t-off] : 0;
    __syncthreads();
    sh[t] += x;
    __syncthreads();
  }
  int excl = (t==0) ? 0 : sh[t-1];
  #pragma unroll
  for(int i=0;i<4;i++){
    int v = excl + base[i];
    rp[t*4+i] = v; wcnt[t*4+i] = v;
  }
  if(t==1023) rp[4096] = excl + s;
}

// ------- MFMA bf16 GEMM body: double-buffered LDS, software-pipelined -------
__device__ __forceinline__ void gemm_body(int bx, int by,
                          const unsigned short* __restrict__ A, const unsigned short* __restrict__ Bt,
                          const float* __restrict__ bias, float* __restrict__ C,
                          unsigned short* __restrict__ Cb, unsigned short* __restrict__ VtT,
                          const unsigned short* __restrict__ Wsd, float* __restrict__ als,
                          float* __restrict__ ald, int M, int K, int N,
                          unsigned short* As, unsigned short* Bs){
  int t = threadIdx.x, lane = t & 63, w = t >> 6;
  int m = lane & 15, g = lane >> 4;
  int bm = by * 64, bn = bx * 64;

  int sr = t >> 3;
  int sc = (t & 7) * 8;
  const unsigned short* Ap = A  + (size_t)(bm + sr)*K + sc;
  const unsigned short* Bp = Bt + (size_t)(bn + sr)*K + sc;
  bool doC = (Wsd != nullptr) && (bx == 0);

  float4v acc[4];
  #pragma unroll
  for(int nt=0;nt<4;nt++) acc[nt] = (float4v){0.f,0.f,0.f,0.f};
  float4v acc2 = (float4v){0.f,0.f,0.f,0.f};

  short8 a0 = *(const short8*)(Ap);
  short8 a1 = *(const short8*)(Ap + 32*K);
  short8 b0 = *(const short8*)(Bp);
  short8 b1 = *(const short8*)(Bp + 32*K);

  int buf = 0;
  for(int k0=0;k0<K;k0+=64){
    *(short8*)&As[buf*4608 + sr*72 + sc]      = a0;
    *(short8*)&As[buf*4608 + (sr+32)*72 + sc] = a1;
    *(short8*)&Bs[buf*4608 + sr*72 + sc]      = b0;
    *(short8*)&Bs[buf*4608 + (sr+32)*72 + sc] = b1;
    if(k0+64 < K){
      a0 = *(const short8*)(Ap + k0+64);
      a1 = *(const short8*)(Ap + 32*K + k0+64);
      b0 = *(const short8*)(Bp + k0+64);
      b1 = *(const short8*)(Bp + 32*K + k0+64);
    }
    __syncthreads();

    #pragma unroll
    for(int ks=0;ks<2;ks++){
      short8 aA = *(const short8*)&As[buf*4608 + (w*16 + m)*72 + ks*32 + g*8];
      #pragma unroll
      for(int nt=0;nt<4;nt++){
        short8 bB = *(const short8*)&Bs[buf*4608 + (nt*16 + m)*72 + ks*32 + g*8];
        acc[nt] = __builtin_amdgcn_mfma_f32_16x16x32_bf16(aA, bB, acc[nt], 0,0,0);
      }
      if(doC){
        short8 bW = *(const short8*)(Wsd + m*K + k0 + ks*32 + g*8);
        acc2 = __builtin_amdgcn_mfma_f32_16x16x32_bf16(aA, bW, acc2, 0,0,0);
      }
    }
    buf ^= 1;
  }

  if(VtT != nullptr && bn >= 512){
    __syncthreads();
    unsigned short* T = As;
    #pragma unroll
    for(int nt=0;nt<4;nt++){
      int col = bn + nt*16 + m;
      float bv = bias ? bias[col] : 0.f;
      unsigned int r0 = __float_as_uint(acc[nt][0]+bv) + 0x8000u;
      unsigned int r1 = __float_as_uint(acc[nt][1]+bv) + 0x8000u;
      unsigned int r2 = __float_as_uint(acc[nt][2]+bv) + 0x8000u;
      unsigned int r3 = __float_as_uint(acc[nt][3]+bv) + 0x8000u;
      uint2 pk;
      pk.x = __builtin_amdgcn_perm(r1, r0, 0x07060302u);
      pk.y = __builtin_amdgcn_perm(r3, r2, 0x07060302u);
      *(uint2*)&T[(nt*16 + m)*72 + w*16 + g*4] = pk;
    }
    __syncthreads();
    int d  = t >> 2;
    int qc = (t & 3) * 16;
    short8 v0 = *(const short8*)&T[d*72 + qc];
    short8 v1 = *(const short8*)&T[d*72 + qc + 8];
    unsigned short* dst = VtT + (size_t)(bn - 512 + d)*M + bm + qc;
    *(short8*)(dst)     = v0;
    *(short8*)(dst + 8) = v1;
    return;
  }

  #pragma unroll
  for(int nt=0;nt<4;nt++){
    int col = bn + nt*16 + m;
    float bv = bias ? bias[col] : 0.f;
    #pragma unroll
    for(int r=0;r<4;r++){
      int row = bm + w*16 + g*4 + r;
      float v = acc[nt][r] + bv;
      if(C)  C[(size_t)row*N + col]  = v;
      if(Cb) Cb[(size_t)row*N + col] = f2bf(v);
    }
  }
  if(doC){
    #pragma unroll
    for(int r=0;r<4;r++){
      int row = bm + w*16 + g*4 + r;
      if(m<4)      als[row*4 + m]     = acc2[r];
      else if(m<8) ald[row*4 + (m-4)] = acc2[r];
    }
  }
}

__global__ __launch_bounds__(256) void gemm_mfma(const unsigned short* __restrict__ A,
                                                 const unsigned short* __restrict__ Bt,
                                                 const float* __restrict__ bias,
                                                 float* __restrict__ C,
                                                 unsigned short* __restrict__ Cb,
                                                 unsigned short* __restrict__ VtT,
                                                 const unsigned short* __restrict__ Wsd,
                                                 float* __restrict__ als,
                                                 float* __restrict__ ald,
                                                 int M, int K, int N){
  __shared__ unsigned short As[2*4608];
  __shared__ unsigned short Bs[2*4608];
  gemm_body(blockIdx.x, blockIdx.y, A, Bt, bias, C, Cb, VtT, Wsd, als, ald, M, K, N, As, Bs);
}

// GEMM layer0 + CSR scatter fused in one dispatch (independent work, both need only scan output)
__global__ __launch_bounds__(256) void gemm0_scatter(const unsigned short* __restrict__ A,
                                                     const unsigned short* __restrict__ Bt,
                                                     unsigned short* __restrict__ Cb,
                                                     const unsigned short* __restrict__ Wsd,
                                                     float* __restrict__ als, float* __restrict__ ald,
                                                     const int* __restrict__ ei, int E, int Etot,
                                                     int* __restrict__ wcnt, int* __restrict__ col){
  __shared__ unsigned short As[2*4608];
  __shared__ unsigned short Bs[2*4608];
  int u = blockIdx.x;
  if(u < 512){
    gemm_body(u & 7, u >> 3, A, Bt, nullptr, nullptr, Cb, nullptr, Wsd, als, ald, 4096, 128, 512, As, Bs);
  } else {
    int e = (u-512)*256 + threadIdx.x;
    if(e < Etot){
      int s,d;
      if(e < E){ s = ei[e]&4095; d = ei[E+e]&4095; } else { s = d = e - E; }
      int pos = atomicAdd(&wcnt[d], 1);
      col[pos] = s;
    }
  }
}

// ------- fused GAT gather + softmax + bias + ELU + LayerNorm (+residual) -------
#define CE 128
__global__ void gat_gather_ln(const int* __restrict__ rp,
                              const int* __restrict__ col,
                              const unsigned short* __restrict__ xlb,
                              const float* __restrict__ als,
                              const float* __restrict__ ald,
                              const float* __restrict__ bias,
                              const float* __restrict__ gw,
                              const float* __restrict__ be,
                              const float* __restrict__ res,
                              float* __restrict__ out,
                              unsigned short* __restrict__ outb,
                              int D, int logC, int do_elu){
  int n = blockIdx.x, t = threadIdx.x;
  int c0 = t*2;
  int h = c0 >> logC;
  int rowW = D >> 1;
  float4 advv = *(const float4*)(ald + n*4);
  int start = rp[n], end = rp[n+1];
  const unsigned int* xw = (const unsigned int*)xlb;

  __shared__ float pw[2][CE*4];
  __shared__ int offs[2][CE];

  float acc0=0.f, acc1=0.f, den=0.f;
  int nch = (end - start + CE - 1) / CE;

  {
    int cnt = min(CE, end-start);
    if(t < cnt){
      int s = col[start+t];
      offs[0][t] = s*rowW;
      float4 av = *(const float4*)(als + s*4);
      #pragma unroll
      for(int hh=0;hh<4;hh++){
        float a = ((const float*)&av)[hh] + ((const float*)&advv)[hh];
        a = a>0.f ? a : 0.2f*a;
        pw[0][t*4+hh] = __expf(a);
      }
    }
  }

  for(int c=0;c<nch;c++){
    __syncthreads();
    if(c+1 < nch){
      int base = start + (c+1)*CE;
      int cnt = min(CE, end-base);
      int b2 = (c+1)&1;
      if(t < cnt){
        int s = col[base+t];
        offs[b2][t] = s*rowW;
        float4 av = *(const float4*)(als + s*4);
        #pragma unroll
        for(int hh=0;hh<4;hh++){
          float a = ((const float*)&av)[hh] + ((const float*)&advv)[hh];
          a = a>0.f ? a : 0.2f*a;
          pw[b2][t*4+hh] = __expf(a);
        }
      }
    }
    int base = start + c*CE;
    int cnt = min(CE, end-base);
    int b = c&1;
    #pragma unroll 8
    for(int j=0;j<cnt;j++){
      float p = pw[b][j*4+h];
      unsigned int u = xw[offs[b][j] + t];
      acc0 += p * bf2f((unsigned short)(u & 0xffffu));
      acc1 += p * bf2f((unsigned short)(u >> 16));
      den += p;
    }
  }

  float inv_d = 1.f/(den + 1e-16f);
  float v0 = acc0*inv_d + bias[c0];
  float v1 = acc1*inv_d + bias[c0+1];
  if(do_elu){
    v0 = v0>0.f ? v0 : expm1f(v0);
    v1 = v1>0.f ? v1 : expm1f(v1);
  }
  __shared__ float sh[4];
  int lane=t&63, wid=t>>6, nw = blockDim.x>>6;
  float sum = waveReduceSum(v0+v1);
  if(lane==0) sh[wid]=sum;
  __syncthreads();
  float mean = 0.f;
  for(int i=0;i<nw;i++) mean += sh[i];
  mean /= (float)D;
  __syncthreads();
  float d0 = v0-mean, d1 = v1-mean;
  float vs = waveReduceSum(d0*d0 + d1*d1);
  if(lane==0) sh[wid]=vs;
  __syncthreads();
  float var = 0.f;
  for(int i=0;i<nw;i++) var += sh[i];
  var /= (float)D;
  float inv = rsqrtf(var + 1e-5f);
  float y0 = d0*inv*gw[c0]   + be[c0];
  float y1 = d1*inv*gw[c0+1] + be[c0+1];
  if(res){ float2 rv = *(const float2*)(res + n*D + c0); y0 += rv.x; y1 += rv.y; }
  if(out) *(float2*)(out + n*D + c0) = make_float2(y0, y1);
  if(outb) ((unsigned int*)outb)[n*rowW + t] =
      (unsigned int)f2bf(y0) | ((unsigned int)f2bf(y1) << 16);
}

// --------- MFMA bf16 MHA: raw v_exp, VALU denominator, KS=2, prefetched staging ---------
#define KS 2
__global__ __launch_bounds__(256) void attention12(const unsigned short* __restrict__ QKV,
                                                   const unsigned short* __restrict__ Vt,
                                                   float* __restrict__ Op,
                                                   float* __restrict__ lp, int S){
  const int RS = 768;
  int qb = blockIdx.x * 64;
  int h  = blockIdx.y;
  int ks = blockIdx.z;
  int t  = threadIdx.x;
  int lane = t & 63, w = t >> 6;
  int m = lane & 15, g = lane >> 4;
  int m7 = m & 7;

  __shared__ unsigned short Ps[64*64];
  __shared__ unsigned short Vs[32*64];
  __shared__ unsigned short Ks[64*36];

  short8 aQ = *(const short8*)(QKV + (qb + w*16 + m)*RS + h*32 + g*8);

  float4v o0 = {0.f,0.f,0.f,0.f}, o1 = {0.f,0.f,0.f,0.f};
  float den = 0.f;

  int r8 = t>>3, c8 = t&7;
  int kr = t>>2, kc = (t&3)*8;
  int kA = ks*(S/KS), kB = kA + S/KS;

  // prologue prefetch
  short8 v  = *(const short8*)(Vt + (h*32 + r8)*S + kA + c8*8);
  short8 kv = *(const short8*)(QKV + (kA + kr)*RS + 256 + h*32 + kc);

  for(int kt=kA; kt<kB; kt+=64){
    __syncthreads();                       // prior iteration done reading Vs/Ks
    *(short8*)&Vs[r8*64 + ((c8 ^ (r8&7))<<3)] = v;
    *(short8*)&Ks[kr*36 + kc] = kv;
    if(kt+64 < kB){                        // issue next tile loads; latency hides under MFMAs
      v  = *(const short8*)(Vt + (h*32 + r8)*S + kt+64 + c8*8);
      kv = *(const short8*)(QKV + (kt+64 + kr)*RS + 256 + h*32 + kc);
    }
    __syncthreads();

    #pragma unroll
    for(int nt=0;nt<4;nt++){
      short8 aK = *(const short8*)&Ks[(nt*16 + m)*36 + g*8];
      float4v acc = {0.f,0.f,0.f,0.f};
      acc = __builtin_amdgcn_mfma_f32_16x16x32_bf16(aK, aQ, acc, 0,0,0);
      float p0 = EXP2(acc[0]);
      float p1 = EXP2(acc[1]);
      float p2 = EXP2(acc[2]);
      float p3 = EXP2(acc[3]);
      den += (p0+p1)+(p2+p3);              // lane's 4 k-slots, all for q = w*16+m
      unsigned int r0 = __float_as_uint(p0) + 0x8000u;
      unsigned int r1 = __float_as_uint(p1) + 0x8000u;
      unsigned int r2 = __float_as_uint(p2) + 0x8000u;
      unsigned int r3 = __float_as_uint(p3) + 0x8000u;
      uint2 pk;
      pk.x = __builtin_amdgcn_perm(r1, r0, 0x07060302u);
      pk.y = __builtin_amdgcn_perm(r3, r2, 0x07060302u);
      *(uint2*)&Ps[(w*16 + m)*64 + (((2*nt + (g>>1)) ^ m7)<<3) + ((g&1)<<2)] = pk;
    }

    #pragma unroll
    for(int kh=0;kh<2;kh++){
      int swz = ((kh*4 + g) ^ m7) << 3;
      short8 aP  = *(const short8*)&Ps[(w*16 + m)*64 + swz];
      short8 bV0 = *(const short8*)&Vs[m*64       + swz];
      short8 bV1 = *(const short8*)&Vs[(16+m)*64  + swz];
      o0 = __builtin_amdgcn_mfma_f32_16x16x32_bf16(aP, bV0, o0, 0,0,0);
      o1 = __builtin_amdgcn_mfma_f32_16x16x32_bf16(aP, bV1, o1, 0,0,0);
    }
  }

  // softmax denominator: reduce across the 4 g-groups (same q = w*16+m)
  den += __shfl_xor(den, 16, 64);
  den += __shfl_xor(den, 32, 64);

  float* Ob = Op + (size_t)ks*S*256;
  #pragma unroll
  for(int r=0;r<4;r++){
    int q = qb + w*16 + g*4 + r;
    Ob[q*256 + h*32 + m]      = o0[r];
    Ob[q*256 + h*32 + 16 + m] = o1[r];
  }
  if(g==0){
    int q = qb + w*16 + m;
    lp[ks*S*8 + q*8 + h] = den;
  }
}

__global__ __launch_bounds__(256) void combine(const float* __restrict__ Op,
                                               const float* __restrict__ lp,
                                               unsigned short* __restrict__ aob, int S){
  int q = blockIdx.x, t = threadIdx.x;
  int h = t >> 5;
  float o = 0.f, l = 0.f;
  #pragma unroll
  for(int s=0;s<KS;s++) o += Op[(size_t)s*S*256 + q*256 + t];
  #pragma unroll
  for(int s=0;s<KS;s++) l += lp[s*S*8 + q*8 + h];
  aob[q*256 + t] = f2bf(o / l);
}

extern "C" void kernel_launch(void* const* d_in, const int* in_sizes, int n_in,
                              void* d_out, int out_size, void* d_ws, size_t ws_size,
                              hipStream_t stream) {
  const float* x   = (const float*)d_in[0];
  const int*   ei  = (const int*)d_in[1];
  const float* W0  = (const float*)d_in[2];
  const float* as0 = (const float*)d_in[3];
  const float* ad0 = (const float*)d_in[4];
  const float* b0  = (const float*)d_in[5];
  const float* W1  = (const float*)d_in[6];
  const float* as1 = (const float*)d_in[7];
  const float* ad1 = (const float*)d_in[8];
  const float* b1  = (const float*)d_in[9];
  const float* W2  = (const float*)d_in[10];
  const float* as2 = (const float*)d_in[11];
  const float* ad2 = (const float*)d_in[12];
  const float* b2  = (const float*)d_in[13];
  const float* g0  = (const float*)d_in[14];
  const float* be0 = (const float*)d_in[15];
  const float* g1  = (const float*)d_in[16];
  const float* be1 = (const float*)d_in[17];
  const float* g2  = (const float*)d_in[18];
  const float* be2 = (const float*)d_in[19];
  const float* wq  = (const float*)d_in[20];
  const float* bq  = (const float*)d_in[21];
  const float* wk  = (const float*)d_in[22];
  const float* bk  = (const float*)d_in[23];
  const float* wv  = (const float*)d_in[24];
  const float* bv  = (const float*)d_in[25];
  const float* wo  = (const float*)d_in[26];
  const float* bo  = (const float*)d_in[27];
  float* out = (float*)d_out;

  const int N = 4096;
  const int E = in_sizes[1] / 2;
  const int Etot = E + N;

  char* p = (char*)d_ws;
  auto alloc = [&](size_t bytes){ char* r = p; p += (bytes + 255) & ~(size_t)255; return r; };

  float* h0   = (float*)alloc(N*512*4);
  float* als  = (float*)alloc(N*4*4);
  float* ald  = (float*)alloc(N*4*4);
  unsigned short* xb   = (unsigned short*)alloc(N*128*2);
  unsigned short* xlb  = (unsigned short*)alloc(N*512*2);
  unsigned short* h0b  = (unsigned short*)alloc(N*512*2);
  unsigned short* h1b  = (unsigned short*)alloc(N*512*2);
  unsigned short* h2b  = (unsigned short*)alloc(N*256*2);
  unsigned short* QKVb = (unsigned short*)alloc((size_t)N*768*2);
  unsigned short* Vt   = (unsigned short*)alloc(256*N*2);
  unsigned short* aob  = (unsigned short*)alloc(N*256*2);
  unsigned short* W0t  = (unsigned short*)alloc(512*128*2);
  unsigned short* W1t  = (unsigned short*)alloc(512*512*2);
  unsigned short* W2t  = (unsigned short*)alloc(256*512*2);
  unsigned short* wqkvt= (unsigned short*)alloc(768*256*2);
  float* bqkv = (float*)alloc(768*4);
  unsigned short* wot  = (unsigned short*)alloc(256*256*2);
  unsigned short* Wsd0 = (unsigned short*)alloc(16*128*2);
  unsigned short* Wsd1 = (unsigned short*)alloc(16*512*2);
  unsigned short* Wsd2 = (unsigned short*)alloc(16*512*2);
  float* Op = (float*)alloc((size_t)KS*N*256*4);
  float* lp = (float*)alloc((size_t)KS*N*8*4);
  int* wcnt = (int*)alloc(N*4);
  int* rp   = (int*)alloc((N+2)*4);
  int* col  = (int*)alloc(Etot*4);

  // ---------- prep (x conv + bqkv + tiled transposes + Wsd) ----------
  prep<<<1585, 256, 0, stream>>>(x, xb, W0, W0t, W1, W1t, W2, W2t,
                                 wq, wk, wv, wqkvt, bq, bk, bv, bqkv, wo, wot,
                                 as0, ad0, Wsd0, as1, ad1, Wsd1, as2, ad2, Wsd2);

  // ---------- CSR hist+scan (1 block, LDS atomics) ----------
  csr_scan<<<1, 1024, 0, stream>>>(ei, E, Etot, rp, wcnt);

  // ---------- GEMM layer 0 (128 -> 512) fused with CSR scatter ----------
  gemm0_scatter<<<512 + (Etot+255)/256, 256, 0, stream>>>(xb, W0t, xlb, Wsd0, als, ald,
                                                          ei, E, Etot, wcnt, col);
  gat_gather_ln<<<N, 256, 0, stream>>>(rp, col, xlb, als, ald, b0, g0, be0,
                                       nullptr, h0, h0b, 512, 7, 1);

  // ---------- GAT layer 1: 512 -> 512, residual ----------
  gemm_mfma<<<dim3(8, 64), 256, 0, stream>>>(h0b, W1t, nullptr, nullptr, xlb, nullptr, Wsd1, als, ald, N, 512, 512);
  gat_gather_ln<<<N, 256, 0, stream>>>(rp, col, xlb, als, ald, b1, g1, be1,
                                       h0, nullptr, h1b, 512, 7, 1);

  // ---------- GAT layer 2: 512 -> 256, 1 head, no ELU ----------
  gemm_mfma<<<dim3(4, 64), 256, 0, stream>>>(h1b, W2t, nullptr, nullptr, xlb, nullptr, Wsd2, als, ald, N, 512, 256);
  gat_gather_ln<<<N, 128, 0, stream>>>(rp, col, xlb, als, ald, b2, g2, be2,
                                       nullptr, nullptr, h2b, 256, 8, 0);

  // ---------- dense MHA ----------
  gemm_mfma<<<dim3(12, 64), 256, 0, stream>>>(h2b, wqkvt, bqkv, nullptr, QKVb, Vt, nullptr, nullptr, nullptr, N, 256, 768);
  attention12<<<dim3(N/64, 8, KS), 256, 0, stream>>>(QKVb, Vt, Op, lp, N);
  combine<<<N, 256, 0, stream>>>(Op, lp, aob, N);
  gemm_mfma<<<dim3(4, 64), 256, 0, stream>>>(aob, wot, bo, out, nullptr, nullptr, nullptr, nullptr, nullptr, N, 256, 256);
}

// Round 6
// 263.395 us; speedup vs baseline: 3.9075x; 1.1449x over previous
//
#include <hip/hip_runtime.h>
#include <math.h>

typedef __attribute__((ext_vector_type(8))) short short8;
typedef __attribute__((ext_vector_type(4))) float float4v;

#define QS 0.2550354f   // (1/sqrt(32)) * log2(e), folded into wq/bq; exp via raw v_exp

#if __has_builtin(__builtin_amdgcn_exp2f)
#define EXP2(x) __builtin_amdgcn_exp2f(x)
#else
#define EXP2(x) __expf((x)*0.6931471805599453f)
#endif

__device__ __forceinline__ float waveReduceSum(float v){
  #pragma unroll
  for(int o=32;o>0;o>>=1) v += __shfl_down(v,o,64);
  return v;
}
__device__ __forceinline__ unsigned short f2bf(float f){
  unsigned int u = __float_as_uint(f);
  return (unsigned short)((u + 0x7FFFu + ((u>>16)&1u)) >> 16);
}
__device__ __forceinline__ float bf2f(unsigned short u){
  return __uint_as_float(((unsigned int)u)<<16);
}

// ------- fused prep: x->bf16 + transposes + qkv concat + Wsd + PARALLEL hist count -------
__global__ __launch_bounds__(256) void prep(const float* __restrict__ x, unsigned short* __restrict__ xb,
                     const float* __restrict__ W0, unsigned short* __restrict__ W0t,
                     const float* __restrict__ W1, unsigned short* __restrict__ W1t,
                     const float* __restrict__ W2, unsigned short* __restrict__ W2t,
                     const float* __restrict__ wq, const float* __restrict__ wk,
                     const float* __restrict__ wv, unsigned short* __restrict__ wqkvt,
                     const float* __restrict__ bq, const float* __restrict__ bk,
                     const float* __restrict__ bv, float* __restrict__ bqkv,
                     const float* __restrict__ wo, unsigned short* __restrict__ wot,
                     const float* __restrict__ as0, const float* __restrict__ ad0, unsigned short* __restrict__ S0,
                     const float* __restrict__ as1, const float* __restrict__ ad1, unsigned short* __restrict__ S1,
                     const float* __restrict__ as2, const float* __restrict__ ad2, unsigned short* __restrict__ S2,
                     const int* __restrict__ ei, int E, int Etot, int* __restrict__ hist){
  int b = blockIdx.x, t = threadIdx.x;
  if(b < 256){
    // x -> bf16, 8 elems/thread (4096*128 = 524288 = 256*256*8)
    int i = (b*256 + t)*8;
    float4 u0 = *(const float4*)(x + i);
    float4 u1 = *(const float4*)(x + i + 4);
    short8 o;
    o[0]=(short)f2bf(u0.x); o[1]=(short)f2bf(u0.y); o[2]=(short)f2bf(u0.z); o[3]=(short)f2bf(u0.w);
    o[4]=(short)f2bf(u1.x); o[5]=(short)f2bf(u1.y); o[6]=(short)f2bf(u1.z); o[7]=(short)f2bf(u1.w);
    *(short8*)(xb + i) = o;
    return;
  }
  if(b == 256){ bqkv[t] = bq[t]*QS; bqkv[256+t] = bk[t]; bqkv[512+t] = bv[t]; return; }
  if(b < 433){
    __shared__ unsigned short tile[64][65];
    int tb = b - 257;   // 176 transpose units
    const float* src; unsigned short* dst; int K,N,roff,local; float sc = 1.f;
    if(tb<16){src=W0;dst=W0t;K=128;N=512;local=tb;roff=0;}
    else if(tb<80){src=W1;dst=W1t;K=512;N=512;local=tb-16;roff=0;}
    else if(tb<112){src=W2;dst=W2t;K=512;N=256;local=tb-80;roff=0;}
    else if(tb<128){src=wq;dst=wqkvt;K=256;N=256;local=tb-112;roff=0;sc=QS;}
    else if(tb<144){src=wk;dst=wqkvt;K=256;N=256;local=tb-128;roff=256;}
    else if(tb<160){src=wv;dst=wqkvt;K=256;N=256;local=tb-144;roff=512;}
    else {src=wo;dst=wot;K=256;N=256;local=tb-160;roff=0;}
    int ntiles = N>>6;
    int k0 = (local/ntiles)*64, n0 = (local%ntiles)*64;
    int r4 = t>>4, c4 = (t&15)*4;
    #pragma unroll
    for(int it=0;it<4;it++){
      int row = r4 + it*16;
      float4 v = *(const float4*)(src + (size_t)(k0+row)*N + n0 + c4);
      tile[row][c4+0]=f2bf(v.x*sc);
      tile[row][c4+1]=f2bf(v.y*sc);
      tile[row][c4+2]=f2bf(v.z*sc);
      tile[row][c4+3]=f2bf(v.w*sc);
    }
    __syncthreads();
    int r8 = t>>3, c8 = (t&7)*8;
    #pragma unroll
    for(int it=0;it<2;it++){
      int n = r8 + it*32;
      short8 o;
      #pragma unroll
      for(int j=0;j<8;j++) o[j] = (short)tile[c8+j][n];
      *(short8*)(dst + (size_t)(n0+n+roff)*K + k0 + c8) = o;
    }
    return;
  }
  if(b >= 1585){
    // parallel histogram (global atomics, whole-GPU)
    int e = (b-1585)*256 + t;
    if(e < Etot){
      int d = (e<E) ? (ei[E+e]&4095) : (e-E);
      atomicAdd(&hist[d], 1);
    }
    return;
  }
  // ---- Wsd build: bb in [0,1152) ----
  int bb = b - 433;
  const float *W,*as,*ad; unsigned short* S; int K,C,H,k;
  if(bb<128){W=W0;as=as0;ad=ad0;S=S0;K=128;C=128;H=4;k=bb;}
  else if(bb<640){W=W1;as=as1;ad=ad1;S=S1;K=512;C=128;H=4;k=bb-128;}
  else {W=W2;as=as2;ad=ad2;S=S2;K=512;C=256;H=1;k=bb-640;}
  int D = H*C;
  __shared__ float s1[4], s2[4];
  int lane=t&63, wid=t>>6;
  for(int h=0;h<H;h++){
    float ps=0.f, pd=0.f;
    for(int c=t;c<C;c+=256){
      float wv2 = W[k*D + h*C + c];
      ps += wv2*as[h*C+c];
      pd += wv2*ad[h*C+c];
    }
    ps = waveReduceSum(ps); pd = waveReduceSum(pd);
    if(lane==0){ s1[wid]=ps; s2[wid]=pd; }
    __syncthreads();
    if(t==0){
      float u=s1[0]+s1[1]+s1[2]+s1[3], v=s2[0]+s2[1]+s2[2]+s2[3];
      S[h*K+k]=f2bf(u); S[(4+h)*K+k]=f2bf(v);
    }
    __syncthreads();
  }
  if(t==0){
    for(int h=H;h<4;h++){ S[h*K+k]=0; S[(4+h)*K+k]=0; }
    for(int r=8;r<16;r++) S[r*K+k]=0;
  }
}

// ---------------- CSR scan only (1 block; hist built in prep) ----------------
__global__ __launch_bounds__(1024) void csr_scan(const int* __restrict__ hist,
                                                 int* __restrict__ rp,
                                                 int* __restrict__ wcnt, int N){
  __shared__ int sh[1024];
  int t = threadIdx.x;
  int base[4];
  int s = 0;
  #pragma unroll
  for(int i=0;i<4;i++){ base[i]=s; s += hist[t*4+i]; }
  sh[t] = s;
  __syncthreads();
  for(int off=1; off<1024; off<<=1){
    int x = (t>=off) ? sh[t-off] : 0;
    __syncthreads();
    sh[t] += x;
    __syncthreads();
  }
  int excl = (t==0) ? 0 : sh[t-1];
  #pragma unroll
  for(int i=0;i<4;i++){
    int v = excl + base[i];
    rp[t*4+i] = v; wcnt[t*4+i] = v;
  }
  if(t==1023) rp[N] = excl + s;
}

// ------- MFMA bf16 GEMM body: double-buffered LDS, software-pipelined -------
__device__ __forceinline__ void gemm_body(int bx, int by,
                          const unsigned short* __restrict__ A, const unsigned short* __restrict__ Bt,
                          const float* __restrict__ bias, float* __restrict__ C,
                          unsigned short* __restrict__ Cb, unsigned short* __restrict__ VtT,
                          const unsigned short* __restrict__ Wsd, float* __restrict__ als,
                          float* __restrict__ ald, int M, int K, int N,
                          unsigned short* As, unsigned short* Bs){
  int t = threadIdx.x, lane = t & 63, w = t >> 6;
  int m = lane & 15, g = lane >> 4;
  int bm = by * 64, bn = bx * 64;

  int sr = t >> 3;
  int sc = (t & 7) * 8;
  const unsigned short* Ap = A  + (size_t)(bm + sr)*K + sc;
  const unsigned short* Bp = Bt + (size_t)(bn + sr)*K + sc;
  bool doC = (Wsd != nullptr) && (bx == 0);

  float4v acc[4];
  #pragma unroll
  for(int nt=0;nt<4;nt++) acc[nt] = (float4v){0.f,0.f,0.f,0.f};
  float4v acc2 = (float4v){0.f,0.f,0.f,0.f};

  short8 a0 = *(const short8*)(Ap);
  short8 a1 = *(const short8*)(Ap + 32*K);
  short8 b0 = *(const short8*)(Bp);
  short8 b1 = *(const short8*)(Bp + 32*K);

  int buf = 0;
  for(int k0=0;k0<K;k0+=64){
    *(short8*)&As[buf*4608 + sr*72 + sc]      = a0;
    *(short8*)&As[buf*4608 + (sr+32)*72 + sc] = a1;
    *(short8*)&Bs[buf*4608 + sr*72 + sc]      = b0;
    *(short8*)&Bs[buf*4608 + (sr+32)*72 + sc] = b1;
    if(k0+64 < K){
      a0 = *(const short8*)(Ap + k0+64);
      a1 = *(const short8*)(Ap + 32*K + k0+64);
      b0 = *(const short8*)(Bp + k0+64);
      b1 = *(const short8*)(Bp + 32*K + k0+64);
    }
    __syncthreads();

    #pragma unroll
    for(int ks=0;ks<2;ks++){
      short8 aA = *(const short8*)&As[buf*4608 + (w*16 + m)*72 + ks*32 + g*8];
      #pragma unroll
      for(int nt=0;nt<4;nt++){
        short8 bB = *(const short8*)&Bs[buf*4608 + (nt*16 + m)*72 + ks*32 + g*8];
        acc[nt] = __builtin_amdgcn_mfma_f32_16x16x32_bf16(aA, bB, acc[nt], 0,0,0);
      }
      if(doC){
        short8 bW = *(const short8*)(Wsd + m*K + k0 + ks*32 + g*8);
        acc2 = __builtin_amdgcn_mfma_f32_16x16x32_bf16(aA, bW, acc2, 0,0,0);
      }
    }
    buf ^= 1;
  }

  if(VtT != nullptr && bn >= 512){
    __syncthreads();
    unsigned short* T = As;
    #pragma unroll
    for(int nt=0;nt<4;nt++){
      int col = bn + nt*16 + m;
      float bv = bias ? bias[col] : 0.f;
      unsigned int r0 = __float_as_uint(acc[nt][0]+bv) + 0x8000u;
      unsigned int r1 = __float_as_uint(acc[nt][1]+bv) + 0x8000u;
      unsigned int r2 = __float_as_uint(acc[nt][2]+bv) + 0x8000u;
      unsigned int r3 = __float_as_uint(acc[nt][3]+bv) + 0x8000u;
      uint2 pk;
      pk.x = __builtin_amdgcn_perm(r1, r0, 0x07060302u);
      pk.y = __builtin_amdgcn_perm(r3, r2, 0x07060302u);
      *(uint2*)&T[(nt*16 + m)*72 + w*16 + g*4] = pk;
    }
    __syncthreads();
    int d  = t >> 2;
    int qc = (t & 3) * 16;
    short8 v0 = *(const short8*)&T[d*72 + qc];
    short8 v1 = *(const short8*)&T[d*72 + qc + 8];
    unsigned short* dst = VtT + (size_t)(bn - 512 + d)*M + bm + qc;
    *(short8*)(dst)     = v0;
    *(short8*)(dst + 8) = v1;
    return;
  }

  #pragma unroll
  for(int nt=0;nt<4;nt++){
    int col = bn + nt*16 + m;
    float bv = bias ? bias[col] : 0.f;
    #pragma unroll
    for(int r=0;r<4;r++){
      int row = bm + w*16 + g*4 + r;
      float v = acc[nt][r] + bv;
      if(C)  C[(size_t)row*N + col]  = v;
      if(Cb) Cb[(size_t)row*N + col] = f2bf(v);
    }
  }
  if(doC){
    #pragma unroll
    for(int r=0;r<4;r++){
      int row = bm + w*16 + g*4 + r;
      if(m<4)      als[row*4 + m]     = acc2[r];
      else if(m<8) ald[row*4 + (m-4)] = acc2[r];
    }
  }
}

__global__ __launch_bounds__(256) void gemm_mfma(const unsigned short* __restrict__ A,
                                                 const unsigned short* __restrict__ Bt,
                                                 const float* __restrict__ bias,
                                                 float* __restrict__ C,
                                                 unsigned short* __restrict__ Cb,
                                                 unsigned short* __restrict__ VtT,
                                                 const unsigned short* __restrict__ Wsd,
                                                 float* __restrict__ als,
                                                 float* __restrict__ ald,
                                                 int M, int K, int N){
  __shared__ unsigned short As[2*4608];
  __shared__ unsigned short Bs[2*4608];
  gemm_body(blockIdx.x, blockIdx.y, A, Bt, bias, C, Cb, VtT, Wsd, als, ald, M, K, N, As, Bs);
}

// GEMM layer0 + CSR scatter fused in one dispatch (independent work, both need only scan output)
__global__ __launch_bounds__(256) void gemm0_scatter(const unsigned short* __restrict__ A,
                                                     const unsigned short* __restrict__ Bt,
                                                     unsigned short* __restrict__ Cb,
                                                     const unsigned short* __restrict__ Wsd,
                                                     float* __restrict__ als, float* __restrict__ ald,
                                                     const int* __restrict__ ei, int E, int Etot,
                                                     int* __restrict__ wcnt, int* __restrict__ col){
  __shared__ unsigned short As[2*4608];
  __shared__ unsigned short Bs[2*4608];
  int u = blockIdx.x;
  if(u < 512){
    gemm_body(u & 7, u >> 3, A, Bt, nullptr, nullptr, Cb, nullptr, Wsd, als, ald, 4096, 128, 512, As, Bs);
  } else {
    int e = (u-512)*256 + threadIdx.x;
    if(e < Etot){
      int s,d;
      if(e < E){ s = ei[e]&4095; d = ei[E+e]&4095; } else { s = d = e - E; }
      int pos = atomicAdd(&wcnt[d], 1);
      col[pos] = s;
    }
  }
}

// ------- fused GAT gather + softmax + bias + ELU + LayerNorm (+residual) -------
#define CE 128
__global__ void gat_gather_ln(const int* __restrict__ rp,
                              const int* __restrict__ col,
                              const unsigned short* __restrict__ xlb,
                              const float* __restrict__ als,
                              const float* __restrict__ ald,
                              const float* __restrict__ bias,
                              const float* __restrict__ gw,
                              const float* __restrict__ be,
                              const float* __restrict__ res,
                              float* __restrict__ out,
                              unsigned short* __restrict__ outb,
                              int D, int logC, int do_elu){
  int n = blockIdx.x, t = threadIdx.x;
  int c0 = t*2;
  int h = c0 >> logC;
  int rowW = D >> 1;
  float4 advv = *(const float4*)(ald + n*4);
  int start = rp[n], end = rp[n+1];
  const unsigned int* xw = (const unsigned int*)xlb;

  __shared__ float pw[2][CE*4];
  __shared__ int offs[2][CE];

  float acc0=0.f, acc1=0.f, den=0.f;
  int nch = (end - start + CE - 1) / CE;

  {
    int cnt = min(CE, end-start);
    if(t < cnt){
      int s = col[start+t];
      offs[0][t] = s*rowW;
      float4 av = *(const float4*)(als + s*4);
      #pragma unroll
      for(int hh=0;hh<4;hh++){
        float a = ((const float*)&av)[hh] + ((const float*)&advv)[hh];
        a = a>0.f ? a : 0.2f*a;
        pw[0][t*4+hh] = __expf(a);
      }
    }
  }

  for(int c=0;c<nch;c++){
    __syncthreads();
    if(c+1 < nch){
      int base = start + (c+1)*CE;
      int cnt = min(CE, end-base);
      int b2 = (c+1)&1;
      if(t < cnt){
        int s = col[base+t];
        offs[b2][t] = s*rowW;
        float4 av = *(const float4*)(als + s*4);
        #pragma unroll
        for(int hh=0;hh<4;hh++){
          float a = ((const float*)&av)[hh] + ((const float*)&advv)[hh];
          a = a>0.f ? a : 0.2f*a;
          pw[b2][t*4+hh] = __expf(a);
        }
      }
    }
    int base = start + c*CE;
    int cnt = min(CE, end-base);
    int b = c&1;
    #pragma unroll 8
    for(int j=0;j<cnt;j++){
      float p = pw[b][j*4+h];
      unsigned int u = xw[offs[b][j] + t];
      acc0 += p * bf2f((unsigned short)(u & 0xffffu));
      acc1 += p * bf2f((unsigned short)(u >> 16));
      den += p;
    }
  }

  float inv_d = 1.f/(den + 1e-16f);
  float v0 = acc0*inv_d + bias[c0];
  float v1 = acc1*inv_d + bias[c0+1];
  if(do_elu){
    v0 = v0>0.f ? v0 : expm1f(v0);
    v1 = v1>0.f ? v1 : expm1f(v1);
  }
  __shared__ float sh[4];
  int lane=t&63, wid=t>>6, nw = blockDim.x>>6;
  float sum = waveReduceSum(v0+v1);
  if(lane==0) sh[wid]=sum;
  __syncthreads();
  float mean = 0.f;
  for(int i=0;i<nw;i++) mean += sh[i];
  mean /= (float)D;
  __syncthreads();
  float d0 = v0-mean, d1 = v1-mean;
  float vs = waveReduceSum(d0*d0 + d1*d1);
  if(lane==0) sh[wid]=vs;
  __syncthreads();
  float var = 0.f;
  for(int i=0;i<nw;i++) var += sh[i];
  var /= (float)D;
  float inv = rsqrtf(var + 1e-5f);
  float y0 = d0*inv*gw[c0]   + be[c0];
  float y1 = d1*inv*gw[c0+1] + be[c0+1];
  if(res){ float2 rv = *(const float2*)(res + n*D + c0); y0 += rv.x; y1 += rv.y; }
  if(out) *(float2*)(out + n*D + c0) = make_float2(y0, y1);
  if(outb) ((unsigned int*)outb)[n*rowW + t] =
      (unsigned int)f2bf(y0) | ((unsigned int)f2bf(y1) << 16);
}

// --------- MFMA bf16 MHA: raw v_exp, VALU denominator, KS=2, prefetched staging ---------
#define KS 2
__global__ __launch_bounds__(256) void attention12(const unsigned short* __restrict__ QKV,
                                                   const unsigned short* __restrict__ Vt,
                                                   float* __restrict__ Op,
                                                   float* __restrict__ lp, int S){
  const int RS = 768;
  int qb = blockIdx.x * 64;
  int h  = blockIdx.y;
  int ks = blockIdx.z;
  int t  = threadIdx.x;
  int lane = t & 63, w = t >> 6;
  int m = lane & 15, g = lane >> 4;
  int m7 = m & 7;

  __shared__ unsigned short Ps[64*64];
  __shared__ unsigned short Vs[32*64];
  __shared__ unsigned short Ks[64*36];

  short8 aQ = *(const short8*)(QKV + (qb + w*16 + m)*RS + h*32 + g*8);

  float4v o0 = {0.f,0.f,0.f,0.f}, o1 = {0.f,0.f,0.f,0.f};
  float den = 0.f;

  int r8 = t>>3, c8 = t&7;
  int kr = t>>2, kc = (t&3)*8;
  int kA = ks*(S/KS), kB = kA + S/KS;

  // prologue prefetch
  short8 v  = *(const short8*)(Vt + (h*32 + r8)*S + kA + c8*8);
  short8 kv = *(const short8*)(QKV + (kA + kr)*RS + 256 + h*32 + kc);

  for(int kt=kA; kt<kB; kt+=64){
    __syncthreads();                       // prior iteration done reading Vs/Ks
    *(short8*)&Vs[r8*64 + ((c8 ^ (r8&7))<<3)] = v;
    *(short8*)&Ks[kr*36 + kc] = kv;
    if(kt+64 < kB){                        // issue next tile loads; latency hides under MFMAs
      v  = *(const short8*)(Vt + (h*32 + r8)*S + kt+64 + c8*8);
      kv = *(const short8*)(QKV + (kt+64 + kr)*RS + 256 + h*32 + kc);
    }
    __syncthreads();

    #pragma unroll
    for(int nt=0;nt<4;nt++){
      short8 aK = *(const short8*)&Ks[(nt*16 + m)*36 + g*8];
      float4v acc = {0.f,0.f,0.f,0.f};
      acc = __builtin_amdgcn_mfma_f32_16x16x32_bf16(aK, aQ, acc, 0,0,0);
      float p0 = EXP2(acc[0]);
      float p1 = EXP2(acc[1]);
      float p2 = EXP2(acc[2]);
      float p3 = EXP2(acc[3]);
      den += (p0+p1)+(p2+p3);              // lane's 4 k-slots, all for q = w*16+m
      unsigned int r0 = __float_as_uint(p0) + 0x8000u;
      unsigned int r1 = __float_as_uint(p1) + 0x8000u;
      unsigned int r2 = __float_as_uint(p2) + 0x8000u;
      unsigned int r3 = __float_as_uint(p3) + 0x8000u;
      uint2 pk;
      pk.x = __builtin_amdgcn_perm(r1, r0, 0x07060302u);
      pk.y = __builtin_amdgcn_perm(r3, r2, 0x07060302u);
      *(uint2*)&Ps[(w*16 + m)*64 + (((2*nt + (g>>1)) ^ m7)<<3) + ((g&1)<<2)] = pk;
    }

    #pragma unroll
    for(int kh=0;kh<2;kh++){
      int swz = ((kh*4 + g) ^ m7) << 3;
      short8 aP  = *(const short8*)&Ps[(w*16 + m)*64 + swz];
      short8 bV0 = *(const short8*)&Vs[m*64       + swz];
      short8 bV1 = *(const short8*)&Vs[(16+m)*64  + swz];
      o0 = __builtin_amdgcn_mfma_f32_16x16x32_bf16(aP, bV0, o0, 0,0,0);
      o1 = __builtin_amdgcn_mfma_f32_16x16x32_bf16(aP, bV1, o1, 0,0,0);
    }
  }

  // softmax denominator: reduce across the 4 g-groups (same q = w*16+m)
  den += __shfl_xor(den, 16, 64);
  den += __shfl_xor(den, 32, 64);

  float* Ob = Op + (size_t)ks*S*256;
  #pragma unroll
  for(int r=0;r<4;r++){
    int q = qb + w*16 + g*4 + r;
    Ob[q*256 + h*32 + m]      = o0[r];
    Ob[q*256 + h*32 + 16 + m] = o1[r];
  }
  if(g==0){
    int q = qb + w*16 + m;
    lp[ks*S*8 + q*8 + h] = den;
  }
}

__global__ __launch_bounds__(256) void combine(const float* __restrict__ Op,
                                               const float* __restrict__ lp,
                                               unsigned short* __restrict__ aob, int S){
  int q = blockIdx.x, t = threadIdx.x;
  int h = t >> 5;
  float o = 0.f, l = 0.f;
  #pragma unroll
  for(int s=0;s<KS;s++) o += Op[(size_t)s*S*256 + q*256 + t];
  #pragma unroll
  for(int s=0;s<KS;s++) l += lp[s*S*8 + q*8 + h];
  aob[q*256 + t] = f2bf(o / l);
}

extern "C" void kernel_launch(void* const* d_in, const int* in_sizes, int n_in,
                              void* d_out, int out_size, void* d_ws, size_t ws_size,
                              hipStream_t stream) {
  const float* x   = (const float*)d_in[0];
  const int*   ei  = (const int*)d_in[1];
  const float* W0  = (const float*)d_in[2];
  const float* as0 = (const float*)d_in[3];
  const float* ad0 = (const float*)d_in[4];
  const float* b0  = (const float*)d_in[5];
  const float* W1  = (const float*)d_in[6];
  const float* as1 = (const float*)d_in[7];
  const float* ad1 = (const float*)d_in[8];
  const float* b1  = (const float*)d_in[9];
  const float* W2  = (const float*)d_in[10];
  const float* as2 = (const float*)d_in[11];
  const float* ad2 = (const float*)d_in[12];
  const float* b2  = (const float*)d_in[13];
  const float* g0  = (const float*)d_in[14];
  const float* be0 = (const float*)d_in[15];
  const float* g1  = (const float*)d_in[16];
  const float* be1 = (const float*)d_in[17];
  const float* g2  = (const float*)d_in[18];
  const float* be2 = (const float*)d_in[19];
  const float* wq  = (const float*)d_in[20];
  const float* bq  = (const float*)d_in[21];
  const float* wk  = (const float*)d_in[22];
  const float* bk  = (const float*)d_in[23];
  const float* wv  = (const float*)d_in[24];
  const float* bv  = (const float*)d_in[25];
  const float* wo  = (const float*)d_in[26];
  const float* bo  = (const float*)d_in[27];
  float* out = (float*)d_out;

  const int N = 4096;
  const int E = in_sizes[1] / 2;
  const int Etot = E + N;

  char* p = (char*)d_ws;
  auto alloc = [&](size_t bytes){ char* r = p; p += (bytes + 255) & ~(size_t)255; return r; };

  float* h0   = (float*)alloc(N*512*4);
  float* als  = (float*)alloc(N*4*4);
  float* ald  = (float*)alloc(N*4*4);
  unsigned short* xb   = (unsigned short*)alloc(N*128*2);
  unsigned short* xlb  = (unsigned short*)alloc(N*512*2);
  unsigned short* h0b  = (unsigned short*)alloc(N*512*2);
  unsigned short* h1b  = (unsigned short*)alloc(N*512*2);
  unsigned short* h2b  = (unsigned short*)alloc(N*256*2);
  unsigned short* QKVb = (unsigned short*)alloc((size_t)N*768*2);
  unsigned short* Vt   = (unsigned short*)alloc(256*N*2);
  unsigned short* aob  = (unsigned short*)alloc(N*256*2);
  unsigned short* W0t  = (unsigned short*)alloc(512*128*2);
  unsigned short* W1t  = (unsigned short*)alloc(512*512*2);
  unsigned short* W2t  = (unsigned short*)alloc(256*512*2);
  unsigned short* wqkvt= (unsigned short*)alloc(768*256*2);
  float* bqkv = (float*)alloc(768*4);
  unsigned short* wot  = (unsigned short*)alloc(256*256*2);
  unsigned short* Wsd0 = (unsigned short*)alloc(16*128*2);
  unsigned short* Wsd1 = (unsigned short*)alloc(16*512*2);
  unsigned short* Wsd2 = (unsigned short*)alloc(16*512*2);
  float* Op = (float*)alloc((size_t)KS*N*256*4);
  float* lp = (float*)alloc((size_t)KS*N*8*4);
  int* hist = (int*)alloc(N*4);
  int* wcnt = (int*)alloc(N*4);
  int* rp   = (int*)alloc((N+2)*4);
  int* col  = (int*)alloc(Etot*4);

  // ---------- prep (x conv + bqkv + transposes + Wsd + parallel hist) ----------
  hipMemsetAsync(hist, 0, N*sizeof(int), stream);
  prep<<<1585 + (Etot+255)/256, 256, 0, stream>>>(x, xb, W0, W0t, W1, W1t, W2, W2t,
                                 wq, wk, wv, wqkvt, bq, bk, bv, bqkv, wo, wot,
                                 as0, ad0, Wsd0, as1, ad1, Wsd1, as2, ad2, Wsd2,
                                 ei, E, Etot, hist);

  // ---------- CSR scan (1 block, prefix only) ----------
  csr_scan<<<1, 1024, 0, stream>>>(hist, rp, wcnt, N);

  // ---------- GEMM layer 0 (128 -> 512) fused with CSR scatter ----------
  gemm0_scatter<<<512 + (Etot+255)/256, 256, 0, stream>>>(xb, W0t, xlb, Wsd0, als, ald,
                                                          ei, E, Etot, wcnt, col);
  gat_gather_ln<<<N, 256, 0, stream>>>(rp, col, xlb, als, ald, b0, g0, be0,
                                       nullptr, h0, h0b, 512, 7, 1);

  // ---------- GAT layer 1: 512 -> 512, residual ----------
  gemm_mfma<<<dim3(8, 64), 256, 0, stream>>>(h0b, W1t, nullptr, nullptr, xlb, nullptr, Wsd1, als, ald, N, 512, 512);
  gat_gather_ln<<<N, 256, 0, stream>>>(rp, col, xlb, als, ald, b1, g1, be1,
                                       h0, nullptr, h1b, 512, 7, 1);

  // ---------- GAT layer 2: 512 -> 256, 1 head, no ELU ----------
  gemm_mfma<<<dim3(4, 64), 256, 0, stream>>>(h1b, W2t, nullptr, nullptr, xlb, nullptr, Wsd2, als, ald, N, 512, 256);
  gat_gather_ln<<<N, 128, 0, stream>>>(rp, col, xlb, als, ald, b2, g2, be2,
                                       nullptr, nullptr, h2b, 256, 8, 0);

  // ---------- dense MHA ----------
  gemm_mfma<<<dim3(12, 64), 256, 0, stream>>>(h2b, wqkvt, bqkv, nullptr, QKVb, Vt, nullptr, nullptr, nullptr, N, 256, 768);
  attention12<<<dim3(N/64, 8, KS), 256, 0, stream>>>(QKVb, Vt, Op, lp, N);
  combine<<<N, 256, 0, stream>>>(Op, lp, aob, N);
  gemm_mfma<<<dim3(4, 64), 256, 0, stream>>>(aob, wot, bo, out, nullptr, nullptr, nullptr, nullptr, nullptr, N, 256, 256);
}